// Round 10
// baseline (143.005 us; speedup 1.0000x reference)
//
#include <hip/hip_runtime.h>
#include <hip/hip_bf16.h>

#define T_DIM 32772
#define NGROUP 2048

typedef short short8v __attribute__((ext_vector_type(8)));
typedef float float4v __attribute__((ext_vector_type(4)));
typedef unsigned int uint4v __attribute__((ext_vector_type(4)));
typedef unsigned int uint2v __attribute__((ext_vector_type(2)));

// packed f32x2 -> bf16x2 (RTNE) -> u32; compiler emits v_cvt_pk_bf16_f32
__device__ __forceinline__ unsigned int f2bf2(float a, float b) {
    __hip_bfloat162 h = __float22bfloat162_rn(make_float2(a, b));
    union { __hip_bfloat162 h; unsigned int u; } c; c.h = h;
    return c.u;
}

__device__ __forceinline__ short8v pack8(const float4v u0, const float4v u1) {
    uint4v p;
    p[0] = f2bf2(u0[0], u0[1]);
    p[1] = f2bf2(u0[2], u0[3]);
    p[2] = f2bf2(u1[0], u1[1]);
    p[3] = f2bf2(u1[2], u1[3]);
    return __builtin_bit_cast(short8v, p);
}

// async global->LDS, 16B/lane; LDS dest = wave-uniform base + lane*16
__device__ __forceinline__ void dma16(const void* g, void* l) {
    __builtin_amdgcn_global_load_lds(
        (const __attribute__((address_space(1))) unsigned int*)g,
        (__attribute__((address_space(3))) unsigned int*)l, 16, 0, 0);
}

// One block per group g (B*H=2048), 8 waves, ~35 KB LDS -> 4 blocks/CU.
// x = targ obs: per-wave register A-frags (wave w owns rows 32w..32w+31), as R9.
// y = preds obs: 8 chunks of 32 rows. Per chunk: global_load_lds -> linear f32
// scratch Fs (wave w owns bytes [w*1K,+1K) and [8K+w*1K,+1K) == its own cvt
// region), then cvt pass -> add-rotate bf16 double-buffer Bs + exact f32 y2.
// Raw s_barrier with lgkmcnt-only drain keeps the next DMA in flight UNDER the
// sweep -> memory pipe never idles. Math identical to R9.
__global__ __launch_bounds__(512) void chamfer_kernel(
    const float* __restrict__ preds, const float* __restrict__ targ,
    float* __restrict__ ch_out)
{
    __shared__ __align__(16) float Fs[4096];              // 16 KB f32 chunk scratch
    __shared__ __align__(16) unsigned short Bs[2][4096];  // 2 x 8 KB bf16 (32 rows)
    __shared__ float y2s[256];
    __shared__ float x2s[256];
    __shared__ float redA[8];
    __shared__ float redB[4];
    // colmin [8][256] = 8 KB aliased onto Fs (dead after last cvt)
    float* colmin_alias = &Fs[0];

    const int g = blockIdx.x;
    const float* gx = targ  + (size_t)g * T_DIM + 4;
    const float* gy = preds + (size_t)g * T_DIM + 4;

    const int tid  = threadIdx.x;
    const int lane = tid & 63;
    const int w    = tid >> 6;   // wave 0..7, owns x rows [32w, 32w+32)
    const int lg   = lane >> 4;  // k-quarter 0..3
    const int lc   = lane & 15;  // row/col within 16-tile

    char* Fsb = (char*)Fs;
    char* Bsb = (char*)Bs;

    // ---- DMA one 32-row y-chunk (16 KB): wave w copies its 2 x 1KB regions ----
    auto dma_chunk = [&](int c) {
        const char* src = (const char*)gy + (size_t)c * 16384;
        const int o0 = w * 1024;
        const int o1 = w * 1024 + 8192;
        dma16(src + o0 + lane * 16, Fsb + o0);
        dma16(src + o1 + lane * 16, Fsb + o1);
    };

    // ---- cvt pass: own-wave f32 -> bf16 (add-rotate) + exact y2 ----
    auto cvt_chunk = [&](int c, int bufsel) {
        const float4v u0 = *reinterpret_cast<const float4v*>(Fsb + tid * 16);
        const float4v u1 = *reinterpret_cast<const float4v*>(Fsb + 8192 + tid * 16);
        float s0 = u0[0]*u0[0] + u0[1]*u0[1] + u0[2]*u0[2] + u0[3]*u0[3];
        float s1 = u1[0]*u1[0] + u1[1]*u1[1] + u1[2]*u1[2] + u1[3]*u1[3];
        #pragma unroll
        for (int s = 1; s < 32; s <<= 1) {
            s0 += __shfl_xor(s0, s);
            s1 += __shfl_xor(s1, s);
        }
        const int r1 = tid >> 5;          // local row 0..15 (piece 1)
        if ((lane & 31) == 0) {
            y2s[c * 32 + r1]      = s0;   // r1 = 2w + (lane>>5)
            y2s[c * 32 + 16 + r1] = s1;
        }
        const int col4 = tid & 31;        // 4-float piece within the row
        const int c16  = col4 >> 1;
        const int sub  = (col4 & 1) * 8;
        char* B = Bsb + bufsel * 8192;
        {
            uint2v p; p[0] = f2bf2(u0[0], u0[1]); p[1] = f2bf2(u0[2], u0[3]);
            const int o = r1 * 256 + ((((c16 & 7) + r1) & 7) << 4) + ((c16 & 8) << 4) + sub;
            *reinterpret_cast<uint2v*>(B + o) = p;
        }
        {
            const int r2 = 16 + r1;
            uint2v p; p[0] = f2bf2(u1[0], u1[1]); p[1] = f2bf2(u1[2], u1[3]);
            const int o = r2 * 256 + ((((c16 & 7) + r2) & 7) << 4) + ((c16 & 8) << 4) + sub;
            *reinterpret_cast<uint2v*>(B + o) = p;
        }
    };

    // ---- issue chunk 0 DMA; it lands during the x-phase ----
    dma_chunk(0);
    __builtin_amdgcn_sched_barrier(0);

    // ---- A fragments to registers + x2 to LDS (own-wave rows; no barrier) ----
    short8v a_frag[2][4];
    #pragma unroll
    for (int ti = 0; ti < 2; ++ti) {
        const float* xr = gx + (size_t)(w * 32 + ti * 16 + lc) * 128;
        float ss = 0.f;
        #pragma unroll
        for (int kk = 0; kk < 4; ++kk) {
            const float4v u0 = *reinterpret_cast<const float4v*>(xr + kk * 32 + lg * 8);
            const float4v u1 = *reinterpret_cast<const float4v*>(xr + kk * 32 + lg * 8 + 4);
            ss += u0[0]*u0[0] + u0[1]*u0[1] + u0[2]*u0[2] + u0[3]*u0[3];
            ss += u1[0]*u1[0] + u1[1]*u1[1] + u1[2]*u1[2] + u1[3]*u1[3];
            a_frag[ti][kk] = pack8(u0, u1);
        }
        ss += __shfl_xor(ss, 16);
        ss += __shfl_xor(ss, 32);
        if (lg == 0) x2s[w * 32 + ti * 16 + lc] = ss; // read only by own wave
    }

    float rowmin[2][4];
    #pragma unroll
    for (int ti = 0; ti < 2; ++ti)
        #pragma unroll
        for (int r = 0; r < 4; ++r) rowmin[ti][r] = 1e30f;
    float cmin[4];

    const int rs0 = ((lg + lc) & 7) << 4;
    const int rs1 = ((lg + lc + 4) & 7) << 4;
    const int x2byte = (w * 32 + lg * 4) * 4; // + ti*64 bytes

    // ---- prologue: chunk 0 cvt, chunk 1 DMA ----
    asm volatile("s_waitcnt vmcnt(0)" ::: "memory");
    __builtin_amdgcn_sched_barrier(0);
    cvt_chunk(0, 0);
    dma_chunk(1);
    asm volatile("s_waitcnt lgkmcnt(0)" ::: "memory");
    __builtin_amdgcn_s_barrier();          // chunk-0 bf16 + y2 visible
    __builtin_amdgcn_sched_barrier(0);

    // ---- 8 chunks: sweep c  ||  DMA(c+1) in flight; then cvt(c+1), DMA(c+2) ----
    #pragma unroll
    for (int c = 0; c < 8; ++c) {
        const char* B = Bsb + (c & 1) * 8192;
        #pragma unroll
        for (int tjl = 0; tjl < 2; ++tjl) {
            const int tj = c * 2 + tjl;
            const int rbyte = (tjl * 16 + lc) * 256;
            const float y2c = y2s[c * 32 + tjl * 16 + lc];

            float4v acc0 = {0.f, 0.f, 0.f, 0.f};
            float4v acc1 = {0.f, 0.f, 0.f, 0.f};
            {
                short8v b0 = *reinterpret_cast<const short8v*>(B + rbyte + rs0);
                short8v b1 = *reinterpret_cast<const short8v*>(B + rbyte + rs1);
                acc0 = __builtin_amdgcn_mfma_f32_16x16x32_bf16(a_frag[0][0], b0, acc0, 0, 0, 0);
                acc1 = __builtin_amdgcn_mfma_f32_16x16x32_bf16(a_frag[1][0], b0, acc1, 0, 0, 0);
                acc0 = __builtin_amdgcn_mfma_f32_16x16x32_bf16(a_frag[0][1], b1, acc0, 0, 0, 0);
                acc1 = __builtin_amdgcn_mfma_f32_16x16x32_bf16(a_frag[1][1], b1, acc1, 0, 0, 0);
                b0 = *reinterpret_cast<const short8v*>(B + rbyte + 128 + rs0);
                b1 = *reinterpret_cast<const short8v*>(B + rbyte + 128 + rs1);
                acc0 = __builtin_amdgcn_mfma_f32_16x16x32_bf16(a_frag[0][2], b0, acc0, 0, 0, 0);
                acc1 = __builtin_amdgcn_mfma_f32_16x16x32_bf16(a_frag[1][2], b0, acc1, 0, 0, 0);
                acc0 = __builtin_amdgcn_mfma_f32_16x16x32_bf16(a_frag[0][3], b1, acc0, 0, 0, 0);
                acc1 = __builtin_amdgcn_mfma_f32_16x16x32_bf16(a_frag[1][3], b1, acc1, 0, 0, 0);
            }

            float cminv = 1e30f;
            {
                const float4v x2a = *reinterpret_cast<const float4v*>((const char*)x2s + x2byte);
                #pragma unroll
                for (int r = 0; r < 4; ++r) {
                    const float t = -2.0f * acc0[r];
                    rowmin[0][r] = fminf(rowmin[0][r], y2c + t);
                    cminv = fminf(cminv, x2a[r] + t);
                }
            }
            {
                const float4v x2b = *reinterpret_cast<const float4v*>((const char*)x2s + x2byte + 64);
                #pragma unroll
                for (int r = 0; r < 4; ++r) {
                    const float t = -2.0f * acc1[r];
                    rowmin[1][r] = fminf(rowmin[1][r], y2c + t);
                    cminv = fminf(cminv, x2b[r] + t);
                }
            }
            cminv = fminf(cminv, __shfl_xor(cminv, 16));
            cminv = fminf(cminv, __shfl_xor(cminv, 32));
            // col = tj*16+lc with tj = s*4+lg  =>  cmin[s] holds col s*64+lane
            if (lg == (tj & 3)) cmin[tj >> 2] = cminv + y2c;
        }

        if (c < 7) {
            asm volatile("s_waitcnt vmcnt(0)" ::: "memory"); // own DMA(c+1) landed
            __builtin_amdgcn_sched_barrier(0);
            cvt_chunk(c + 1, (c + 1) & 1);   // reads ONLY own-wave Fs region
            if (c < 6) dma_chunk(c + 2);     // own Fs region free; rides next sweep
        }
        asm volatile("s_waitcnt lgkmcnt(0)" ::: "memory");   // my LDS writes done
        __builtin_amdgcn_s_barrier();                        // NO vmcnt drain
        __builtin_amdgcn_sched_barrier(0);
    }

    // ---- per-wave col-mins -> aliased LDS (Fs dead: last cvt was chunk 7) ----
    #pragma unroll
    for (int s = 0; s < 4; ++s)
        colmin_alias[w * 256 + s * 64 + lane] = cmin[s];

    // ---- loss2: row-mins; add x2[row] at the end ----
    float s2 = 0.f;
    #pragma unroll
    for (int ti = 0; ti < 2; ++ti) {
        const float4v x2v = *reinterpret_cast<const float4v*>((const char*)x2s + x2byte + ti * 64);
        #pragma unroll
        for (int r = 0; r < 4; ++r) {
            float v = rowmin[ti][r];
            v = fminf(v, __shfl_xor(v, 1));
            v = fminf(v, __shfl_xor(v, 2));
            v = fminf(v, __shfl_xor(v, 4));
            v = fminf(v, __shfl_xor(v, 8));
            s2 += x2v[r] + v;
        }
    }
    s2 += __shfl_xor(s2, 16);
    s2 += __shfl_xor(s2, 32);
    if (lane == 0) redA[w] = s2;
    __syncthreads();

    // ---- loss1: min over 8 waves per col (y2 folded), sum over 256 cols ----
    if (tid < 256) {
        float m = colmin_alias[tid];
        #pragma unroll
        for (int ww = 1; ww < 8; ++ww) m = fminf(m, colmin_alias[ww * 256 + tid]);
        #pragma unroll
        for (int s = 1; s < 64; s <<= 1) m += __shfl_xor(m, s);
        if (lane == 0) redB[w] = m;
    }
    __syncthreads();
    if (tid == 0) {
        const float l1 = redB[0] + redB[1] + redB[2] + redB[3];
        float l2 = 0.f;
        #pragma unroll
        for (int ww = 0; ww < 8; ++ww) l2 += redA[ww];
        ch_out[g] = l1 + l2;
    }
}

// Action loss + final reduction -> out[0], out[1]
__global__ __launch_bounds__(256) void final_kernel(
    const float* __restrict__ preds, const float* __restrict__ targ,
    const float* __restrict__ ch, float* __restrict__ out)
{
    __shared__ float rsw[4], rsa[4], rsc[4];
    const int tid = threadIdx.x;
    const int lane = tid & 63, w = tid >> 6;
    float sw = 0.f, sa0 = 0.f, sc = 0.f;
    for (int p = tid; p < NGROUP; p += 256) {
        const float* pp = preds + (size_t)p * T_DIM;
        const float* tt = targ  + (size_t)p * T_DIM;
        float al = 0.f;
        #pragma unroll
        for (int d = 0; d < 4; ++d) { const float df = pp[d] - tt[d]; al += df * df; }
        al *= 0.25f;
        if ((p & 31) == 0) { sw += 10.f * al; sa0 += al; }
        else               { sw += al; }
        sc += ch[p];
    }
    #pragma unroll
    for (int s = 1; s < 64; s <<= 1) {
        sw  += __shfl_xor(sw, s);
        sa0 += __shfl_xor(sa0, s);
        sc  += __shfl_xor(sc, s);
    }
    if (lane == 0) { rsw[w] = sw; rsa[w] = sa0; rsc[w] = sc; }
    __syncthreads();
    if (tid == 0) {
        float tsw = 0.f, tsa = 0.f, tsc = 0.f;
        #pragma unroll
        for (int i = 0; i < 4; ++i) { tsw += rsw[i]; tsa += rsa[i]; tsc += rsc[i]; }
        out[0] = tsw / 2048.f + tsc / 2048.f;
        out[1] = tsa / 64.f;
    }
}

extern "C" void kernel_launch(void* const* d_in, const int* in_sizes, int n_in,
                              void* d_out, int out_size, void* d_ws, size_t ws_size,
                              hipStream_t stream) {
    const float* preds = (const float*)d_in[0];
    const float* targ  = (const float*)d_in[1];
    float* out = (float*)d_out;
    float* ch  = (float*)d_ws; // 2048 floats of per-group chamfer
    chamfer_kernel<<<NGROUP, 512, 0, stream>>>(preds, targ, ch);
    final_kernel<<<1, 256, 0, stream>>>(preds, targ, ch, out);
}

// Round 11
// 119.828 us; speedup vs baseline: 1.1934x; 1.1934x over previous
//
#include <hip/hip_runtime.h>
#include <hip/hip_bf16.h>

#define T_DIM 32772
#define NGROUP 2048

typedef short short8v __attribute__((ext_vector_type(8)));
typedef float float4v __attribute__((ext_vector_type(4)));
typedef unsigned int uint4v __attribute__((ext_vector_type(4)));

// packed f32x2 -> bf16x2 (RTNE) -> u32; compiler emits v_cvt_pk_bf16_f32
__device__ __forceinline__ unsigned int f2bf2(float a, float b) {
    __hip_bfloat162 h = __float22bfloat162_rn(make_float2(a, b));
    union { __hip_bfloat162 h; unsigned int u; } c; c.h = h;
    return c.u;
}

__device__ __forceinline__ short8v pack8(const float4v u0, const float4v u1) {
    uint4v p;
    p[0] = f2bf2(u0[0], u0[1]);
    p[1] = f2bf2(u0[2], u0[3]);
    p[2] = f2bf2(u1[0], u1[1]);
    p[3] = f2bf2(u1[2], u1[3]);
    return __builtin_bit_cast(short8v, p);
}

// One block per chamfer group g (B*H=2048), 8 waves, ~34.4 KB LDS -> 4 blocks/CU.
// x = targ obs (n, 256x128): per-wave register A-frags (wave w owns rows 32w..32w+31).
// y = preds obs (m, 256x128): staged in 2 halves of 128 rows (32 KB bf16, add-rotate
//     layout: 16B chunk c of row r at r*256 + (((c&7)+r)&7)*16 + ((c&8)<<4)).
// Each half's 8-col-tile sweep is barrier-free; 4 blocks/CU stagger so staging
// of one block hides under sweeps of the others.
// P = x2[n] + y2[m] - 2*x.y ; loss1 = sum_m min_n P ; loss2 = sum_n min_m P
__global__ __launch_bounds__(512) void chamfer_kernel(
    const float* __restrict__ preds, const float* __restrict__ targ,
    float* __restrict__ ch_out)
{
    __shared__ __align__(16) unsigned short Ys[128 * 128]; // 32 KB bf16 (half of y)
    __shared__ float y2s[128];
    __shared__ float x2s[256];
    __shared__ float redA[8];
    __shared__ float redB[4];
    // colmin [8][256] aliased onto Ys (dead after the final sweep barrier)
    float* colmin_alias = reinterpret_cast<float*>(&Ys[0]);

    const int g = blockIdx.x;
    const float* gx = targ  + (size_t)g * T_DIM + 4;
    const float* gy = preds + (size_t)g * T_DIM + 4;

    const int tid  = threadIdx.x;
    const int lane = tid & 63;
    const int w    = tid >> 6;   // wave 0..7, owns x rows [32w, 32w+32)
    const int lg   = lane >> 4;  // k-quarter 0..3
    const int lc   = lane & 15;  // row/col within 16-tile

    char* Ysb = (char*)Ys;

    // staging decomposition: 4 threads per row (128 rows), thread owns 32 floats
    const int prow = tid >> 2;   // row within half 0..127
    const int q    = tid & 3;    // quarter of the row

    // ---- A fragments to registers + x2 to LDS (own-wave rows) ----
    short8v a_frag[2][4];
    #pragma unroll
    for (int ti = 0; ti < 2; ++ti) {
        const float* xr = gx + (size_t)(w * 32 + ti * 16 + lc) * 128;
        float ss = 0.f;
        #pragma unroll
        for (int kk = 0; kk < 4; ++kk) {
            const float4v u0 = *reinterpret_cast<const float4v*>(xr + kk * 32 + lg * 8);
            const float4v u1 = *reinterpret_cast<const float4v*>(xr + kk * 32 + lg * 8 + 4);
            ss += u0[0]*u0[0] + u0[1]*u0[1] + u0[2]*u0[2] + u0[3]*u0[3];
            ss += u1[0]*u1[0] + u1[1]*u1[1] + u1[2]*u1[2] + u1[3]*u1[3];
            a_frag[ti][kk] = pack8(u0, u1);
        }
        ss += __shfl_xor(ss, 16);
        ss += __shfl_xor(ss, 32);
        if (lg == 0) x2s[w * 32 + ti * 16 + lc] = ss; // read only by own wave
    }

    float rowmin[2][4];
    #pragma unroll
    for (int ti = 0; ti < 2; ++ti)
        #pragma unroll
        for (int r = 0; r < 4; ++r) rowmin[ti][r] = 1e30f;
    float cmin[4];

    // read slots (conflict-free add-rotate; b_frag[kk] = chunk 4kk+lg of row)
    const int rs0 = ((lg + lc) & 7) << 4;
    const int rs1 = ((lg + lc + 4) & 7) << 4;
    const int x2byte = (w * 32 + lg * 4) * 4; // + ti*64 bytes

    // ---- two halves: stage 128 y-rows -> barrier -> barrier-free 8-tile sweep ----
    #pragma unroll
    for (int h = 0; h < 2; ++h) {
        // stage half h (register-light: 2 sequential batches of 4 x float4)
        {
            const float* src = gy + (size_t)(h * 128 + prow) * 128 + q * 32;
            float ss = 0.f;
            #pragma unroll
            for (int j = 0; j < 2; ++j) {
                const float4v u0 = *reinterpret_cast<const float4v*>(src + j * 16);
                const float4v u1 = *reinterpret_cast<const float4v*>(src + j * 16 + 4);
                const float4v u2 = *reinterpret_cast<const float4v*>(src + j * 16 + 8);
                const float4v u3 = *reinterpret_cast<const float4v*>(src + j * 16 + 12);
                ss += u0[0]*u0[0] + u0[1]*u0[1] + u0[2]*u0[2] + u0[3]*u0[3];
                ss += u1[0]*u1[0] + u1[1]*u1[1] + u1[2]*u1[2] + u1[3]*u1[3];
                ss += u2[0]*u2[0] + u2[1]*u2[1] + u2[2]*u2[2] + u2[3]*u2[3];
                ss += u3[0]*u3[0] + u3[1]*u3[1] + u3[2]*u3[2] + u3[3]*u3[3];
                const int c0 = q * 4 + 2 * j;
                const int c1 = c0 + 1;
                const int o0 = prow * 256 + ((((c0 & 7) + prow) & 7) << 4) + ((c0 & 8) << 4);
                const int o1 = prow * 256 + ((((c1 & 7) + prow) & 7) << 4) + ((c1 & 8) << 4);
                *reinterpret_cast<short8v*>(Ysb + o0) = pack8(u0, u1);
                *reinterpret_cast<short8v*>(Ysb + o1) = pack8(u2, u3);
            }
            ss += __shfl_xor(ss, 1);
            ss += __shfl_xor(ss, 2);
            if (q == 0) y2s[prow] = ss;
        }
        __syncthreads(); // half h staged

        // barrier-free sweep over this half's 8 col-tiles
        #pragma unroll
        for (int tjl = 0; tjl < 8; ++tjl) {
            const int rbyte = (tjl * 16 + lc) * 256;
            const float y2c = y2s[tjl * 16 + lc];

            float4v acc0 = {0.f, 0.f, 0.f, 0.f};
            float4v acc1 = {0.f, 0.f, 0.f, 0.f};
            {
                short8v b0 = *reinterpret_cast<const short8v*>(Ysb + rbyte + rs0);
                short8v b1 = *reinterpret_cast<const short8v*>(Ysb + rbyte + rs1);
                acc0 = __builtin_amdgcn_mfma_f32_16x16x32_bf16(a_frag[0][0], b0, acc0, 0, 0, 0);
                acc1 = __builtin_amdgcn_mfma_f32_16x16x32_bf16(a_frag[1][0], b0, acc1, 0, 0, 0);
                acc0 = __builtin_amdgcn_mfma_f32_16x16x32_bf16(a_frag[0][1], b1, acc0, 0, 0, 0);
                acc1 = __builtin_amdgcn_mfma_f32_16x16x32_bf16(a_frag[1][1], b1, acc1, 0, 0, 0);
                b0 = *reinterpret_cast<const short8v*>(Ysb + rbyte + 128 + rs0);
                b1 = *reinterpret_cast<const short8v*>(Ysb + rbyte + 128 + rs1);
                acc0 = __builtin_amdgcn_mfma_f32_16x16x32_bf16(a_frag[0][2], b0, acc0, 0, 0, 0);
                acc1 = __builtin_amdgcn_mfma_f32_16x16x32_bf16(a_frag[1][2], b0, acc1, 0, 0, 0);
                acc0 = __builtin_amdgcn_mfma_f32_16x16x32_bf16(a_frag[0][3], b1, acc0, 0, 0, 0);
                acc1 = __builtin_amdgcn_mfma_f32_16x16x32_bf16(a_frag[1][3], b1, acc1, 0, 0, 0);
            }

            float cminv = 1e30f;
            {
                const float4v x2a = *reinterpret_cast<const float4v*>((const char*)x2s + x2byte);
                #pragma unroll
                for (int r = 0; r < 4; ++r) {
                    const float t = -2.0f * acc0[r];
                    rowmin[0][r] = fminf(rowmin[0][r], y2c + t);
                    cminv = fminf(cminv, x2a[r] + t);
                }
            }
            {
                const float4v x2b = *reinterpret_cast<const float4v*>((const char*)x2s + x2byte + 64);
                #pragma unroll
                for (int r = 0; r < 4; ++r) {
                    const float t = -2.0f * acc1[r];
                    rowmin[1][r] = fminf(rowmin[1][r], y2c + t);
                    cminv = fminf(cminv, x2b[r] + t);
                }
            }
            // min over the wave's 32 rows; fold y2 (col-constant) here
            cminv = fminf(cminv, __shfl_xor(cminv, 16));
            cminv = fminf(cminv, __shfl_xor(cminv, 32));
            // col = h*128 + (tjl>>2)*64 + lane
            if (lg == (tjl & 3)) cmin[h * 2 + (tjl >> 2)] = cminv + y2c;
        }

        __syncthreads(); // all waves done reading Ys/y2s before re-stage / alias
    }

    // ---- per-wave col-mins -> aliased LDS (Ys dead now) ----
    #pragma unroll
    for (int s = 0; s < 4; ++s)
        colmin_alias[w * 256 + s * 64 + lane] = cmin[s];

    // ---- loss2: row-mins; add x2[row] at the end ----
    float s2 = 0.f;
    #pragma unroll
    for (int ti = 0; ti < 2; ++ti) {
        const float4v x2v = *reinterpret_cast<const float4v*>((const char*)x2s + x2byte + ti * 64);
        #pragma unroll
        for (int r = 0; r < 4; ++r) {
            float v = rowmin[ti][r];
            v = fminf(v, __shfl_xor(v, 1));
            v = fminf(v, __shfl_xor(v, 2));
            v = fminf(v, __shfl_xor(v, 4));
            v = fminf(v, __shfl_xor(v, 8));
            s2 += x2v[r] + v;
        }
    }
    s2 += __shfl_xor(s2, 16);
    s2 += __shfl_xor(s2, 32);
    if (lane == 0) redA[w] = s2;
    __syncthreads();

    // ---- loss1: min over 8 waves per col (y2 folded), sum over 256 cols ----
    if (tid < 256) {
        float m = colmin_alias[tid];
        #pragma unroll
        for (int ww = 1; ww < 8; ++ww) m = fminf(m, colmin_alias[ww * 256 + tid]);
        #pragma unroll
        for (int s = 1; s < 64; s <<= 1) m += __shfl_xor(m, s);
        if (lane == 0) redB[w] = m;
    }
    __syncthreads();
    if (tid == 0) {
        const float l1 = redB[0] + redB[1] + redB[2] + redB[3];
        float l2 = 0.f;
        #pragma unroll
        for (int ww = 0; ww < 8; ++ww) l2 += redA[ww];
        ch_out[g] = l1 + l2;
    }
}

// Action loss + final reduction -> out[0], out[1]
__global__ __launch_bounds__(256) void final_kernel(
    const float* __restrict__ preds, const float* __restrict__ targ,
    const float* __restrict__ ch, float* __restrict__ out)
{
    __shared__ float rsw[4], rsa[4], rsc[4];
    const int tid = threadIdx.x;
    const int lane = tid & 63, w = tid >> 6;
    float sw = 0.f, sa0 = 0.f, sc = 0.f;
    for (int p = tid; p < NGROUP; p += 256) {
        const float* pp = preds + (size_t)p * T_DIM;
        const float* tt = targ  + (size_t)p * T_DIM;
        float al = 0.f;
        #pragma unroll
        for (int d = 0; d < 4; ++d) { const float df = pp[d] - tt[d]; al += df * df; }
        al *= 0.25f;
        if ((p & 31) == 0) { sw += 10.f * al; sa0 += al; }
        else               { sw += al; }
        sc += ch[p];
    }
    #pragma unroll
    for (int s = 1; s < 64; s <<= 1) {
        sw  += __shfl_xor(sw, s);
        sa0 += __shfl_xor(sa0, s);
        sc  += __shfl_xor(sc, s);
    }
    if (lane == 0) { rsw[w] = sw; rsa[w] = sa0; rsc[w] = sc; }
    __syncthreads();
    if (tid == 0) {
        float tsw = 0.f, tsa = 0.f, tsc = 0.f;
        #pragma unroll
        for (int i = 0; i < 4; ++i) { tsw += rsw[i]; tsa += rsa[i]; tsc += rsc[i]; }
        out[0] = tsw / 2048.f + tsc / 2048.f;
        out[1] = tsa / 64.f;
    }
}

extern "C" void kernel_launch(void* const* d_in, const int* in_sizes, int n_in,
                              void* d_out, int out_size, void* d_ws, size_t ws_size,
                              hipStream_t stream) {
    const float* preds = (const float*)d_in[0];
    const float* targ  = (const float*)d_in[1];
    float* out = (float*)d_out;
    float* ch  = (float*)d_ws; // 2048 floats of per-group chamfer
    chamfer_kernel<<<NGROUP, 512, 0, stream>>>(preds, targ, ch);
    final_kernel<<<1, 256, 0, stream>>>(preds, targ, ch, out);
}